// Round 9
// baseline (330.513 us; speedup 1.0000x reference)
//
#include <hip/hip_runtime.h>
#include <math.h>

#define FLAT   8192
#define NB     64
#define OD_    80
#define NE_    512
#define EATT_  4096
#define MAXACT 4096
// acc_glob: 96 floats/node, atomically accumulated by k_rgemm:
//   [0..31]  out_s partial (pre gate/env/norm)
//   [32..47] q (scalar coeff that multiplies yv)
//   [48..95] D-term out_v, layout comp*16 + o
#define ACCW 96

__device__ __forceinline__ float silu_f(float x) { return x / (1.f + __expf(-x)); }
__device__ __forceinline__ float sigm_f(float x) { return 1.f / (1.f + __expf(-x)); }

// ---------------- init: zero acc + vabs, widx=-1, count=0 ----------------
__global__ void k_init(float* acc, float* vabs, int* widx, int* count) {
  int t = blockIdx.x * 256 + threadIdx.x;
  if (t < MAXACT * ACCW) acc[t] = 0.f;
  if (t < FLAT) widx[t] = -1;
  if (t < NB * OD_) vabs[t] = 0.f;
  if (t == 0) *count = 0;
}

// ---------------- scatter: last-write-wins == max edge index ----------------
__global__ void k_scatter(const int* __restrict__ att_dst, int* widx) {
  int i = blockIdx.x * 256 + threadIdx.x;
  if (i < EATT_) atomicMax(&widx[att_dst[i]], i);
}

// ---------------- compact active-node list ----------------
__global__ void k_build(const int* __restrict__ widx, int* active, int* count) {
  int j = blockIdx.x * 256 + threadIdx.x;
  if (j < FLAT && widx[j] >= 0) {
    int p = atomicAdd(count, 1);
    active[p] = j;
  }
}

// ---------------- per-batch absorber row of gate layer 1: h_abs @ wg1 ----------------
__global__ void k_gabs(const int* __restrict__ abs_idx, const float* __restrict__ h,
                       const float* __restrict__ wg1, float* habs_g) {
  int b = blockIdx.x;   // 64
  int t = threadIdx.x;  // 128
  __shared__ float hs[128];
  int nabs = abs_idx[b];
  hs[t] = h[(size_t)(b * 128 + nabs) * 128 + t];
  __syncthreads();
  float g = 0.f;
  for (int c = 0; c < 128; ++c) g = fmaf(hs[c], wg1[c * 128 + t], g);
  habs_g[b * 128 + t] = g;
}

// ---------------- per active node: rbf, hidden a(128), gate, env, coefs ----------------
__global__ void k_node(const int* __restrict__ count, const int* __restrict__ active,
                       const int* __restrict__ widx,
                       const float* __restrict__ att_dist, const float* __restrict__ att_vec,
                       const int* __restrict__ z, const float* __restrict__ w_zemb,
                       const int* __restrict__ abs_idx,
                       const float* __restrict__ w1_rad, const float* __restrict__ b1_rad,
                       const float* __restrict__ h, const float* __restrict__ habs_g,
                       const float* __restrict__ wg1, const float* __restrict__ bg1,
                       const float* __restrict__ wg2, const float* __restrict__ bg2,
                       const float* __restrict__ h_full,
                       float* a_glob, float* coef_glob, float* meta_f, int* meta_b) {
  int pos = blockIdx.x;
  if (pos >= *count) return;
  int t = threadIdx.x;  // 128 threads
  __shared__ float win[49];
  __shared__ float yv_s[3];
  __shared__ float red[128];
  __shared__ float sh_d;

  int j = active[pos];
  int b = j >> 7;
  int n = j & 127;
  int e = widx[j];

  if (t == 0) {
    float d = att_dist[e];
    sh_d = d;
    float eps = fmaxf(d, 1e-8f);
    const float s3 = 1.7320508075688772f;
    yv_s[0] = s3 * att_vec[e * 3 + 0] / eps;
    yv_s[1] = s3 * att_vec[e * 3 + 1] / eps;
    yv_s[2] = s3 * att_vec[e * 3 + 2] / eps;
  }
  int nabs = abs_idx[b];
  float isab = (n == nabs) ? 1.f : 0.f;
  if (t < 32) win[t] = w_zemb[z[j] * 32 + t];
  if (t == 32) win[32] = isab;
  if (t >= 33 && t < 49) {
    int k = t - 33;
    float d = att_dist[e];
    float x = (d - (float)k * (1.f / 3.f)) * 3.f;  // width = CUTOFF/(RBF-1) = 1/3
    win[t] = __expf(-0.5f * x * x);
  }
  __syncthreads();

  // hidden a = silu(win @ w1_rad + b1_rad)   (49 -> 128)
  {
    float s = b1_rad[t];
    for (int k = 0; k < 49; ++k) s = fmaf(win[k], w1_rad[k * 128 + t], s);
    a_glob[pos * 128 + t] = silu_f(s);
  }

  // gate MLP hidden (273 -> 128); h_abs part precomputed per-batch (k_gabs)
  {
    float g = bg1[t] + habs_g[b * 128 + t];
    const float* hn = h + (size_t)j * 128;
    for (int c = 0; c < 128; ++c) g = fmaf(hn[c], wg1[(128 + c) * 128 + t], g);
    for (int k = 0; k < 16; ++k)  g = fmaf(win[33 + k], wg1[(256 + k) * 128 + t], g);
    g = fmaf(isab, wg1[272 * 128 + t], g);
    red[t] = silu_f(g) * wg2[t];
  }
  __syncthreads();

  // per-node contraction coefficients: [s1(64), p*inv_s3(32), v1(96)]
  const float* hf = h_full + (size_t)j * 160;
  if (t < 64) coef_glob[pos * 192 + t] = hf[t];
  if (t >= 64 && t < 96) {
    int i = t - 64;
    float pv = hf[64 + i * 3 + 0] * yv_s[0] + hf[64 + i * 3 + 1] * yv_s[1] +
               hf[64 + i * 3 + 2] * yv_s[2];
    coef_glob[pos * 192 + t] = pv * 0.5773502691896258f;
  }
  if (t < 96) coef_glob[pos * 192 + 96 + t] = hf[64 + t];

  if (t == 0) {
    float tot = 0.f;
    for (int k = 0; k < 128; ++k) tot += red[k];
    tot += bg2[0];
    float gate = sigm_f(tot);
    float d = sh_d;
    float env = (d < 5.f) ? 0.5f * (__cosf(3.14159265358979323846f * d * 0.2f) + 1.f) : 0.f;
    meta_f[pos * 4 + 0] = yv_s[0];
    meta_f[pos * 4 + 1] = yv_s[1];
    meta_f[pos * 4 + 2] = yv_s[2];
    meta_f[pos * 4 + 3] = gate * env;
    meta_b[pos] = b;
  }
}

// ---------------- radial GEMM + fused contraction (8x8 register tile) ----------------
// R8 post-mortem: the 4n x 8c thread tile reads 48B LDS per 64 FLOP
// (0.75 B/FLOP) vs ~0.33 sustainable on the per-CU LDS pipe (~85 B/cyc vs
// 256 FLOP/cyc) -> LDS-BW-bound at 44% VALU. Now: block 128 nodes x 128 cols
// (grid 36 x 32), thread 8n x 8c = 64 acc; 64B LDS per 128 FLOP (0.5).
// VGPR discipline (84 RA cap, R5/R6 lesson): staging is store-immediately
// (temps die before compute); inner k-step split in two a-halves so peak live
// ~= 64 acc + 12 operands. Cols per thread: q*64 + tx*4 + e (conflict-free).
__global__ __launch_bounds__(256) void k_rgemm(const int* __restrict__ count,
                                               const float* __restrict__ a_glob,
                                               const float* __restrict__ coef_glob,
                                               const float* __restrict__ w2,
                                               const float* __restrict__ b2,
                                               float* __restrict__ acc_glob) {
  int cc = blockIdx.x;          // 0..35 (col chunk of 128)
  int nbase = blockIdx.y * 128;
  if (nbase >= *count) return;
  int t = threadIdx.x;
  int tx = t & 15, ty = t >> 4;
  int n0 = ty * 8;

  __shared__ float w_s[2][16][128];  // 16 KB
  __shared__ float a_s[2][16][128];  // 16 KB (transposed [k][node])

  const float* wbase = w2 + cc * 128;
  int wr = t >> 5;             // 0..7; rows wr and wr+8
  int wc4 = t & 31;            // col/4
  int anode = t >> 1;          // 0..127
  int aq = (t & 1) * 8;        // k-offset of this thread's 8 a-floats
  const float* aptr = a_glob + (size_t)(nbase + anode) * 128 + aq;

  // stage tile 0
  {
    float4 wv0 = *(const float4*)(wbase + (size_t)wr * 4608 + wc4 * 4);
    float4 wv1 = *(const float4*)(wbase + (size_t)(wr + 8) * 4608 + wc4 * 4);
    float4 av0 = *(const float4*)(aptr);
    float4 av1 = *(const float4*)(aptr + 4);
    *(float4*)&w_s[0][wr][wc4 * 4]     = wv0;
    *(float4*)&w_s[0][wr + 8][wc4 * 4] = wv1;
    a_s[0][aq + 0][anode] = av0.x; a_s[0][aq + 1][anode] = av0.y;
    a_s[0][aq + 2][anode] = av0.z; a_s[0][aq + 3][anode] = av0.w;
    a_s[0][aq + 4][anode] = av1.x; a_s[0][aq + 5][anode] = av1.y;
    a_s[0][aq + 6][anode] = av1.z; a_s[0][aq + 7][anode] = av1.w;
  }
  __syncthreads();

  // acc[i][j], j = q*4+e <-> global col cc*128 + q*64 + tx*4 + e; i = node n0+i
  float acc[8][8];
#pragma unroll
  for (int i = 0; i < 8; ++i)
#pragma unroll
    for (int j = 0; j < 8; ++j) acc[i][j] = 0.f;

  for (int kb = 0; kb < 8; ++kb) {
    int cur = kb & 1;
    if (kb < 7) {
      // load + store immediately into the other buffer (regs die here)
      int nxt = cur ^ 1;
      float4 wv0 = *(const float4*)(wbase + (size_t)((kb + 1) * 16 + wr) * 4608 + wc4 * 4);
      float4 wv1 = *(const float4*)(wbase + (size_t)((kb + 1) * 16 + wr + 8) * 4608 + wc4 * 4);
      float4 av0 = *(const float4*)(aptr + (kb + 1) * 16);
      float4 av1 = *(const float4*)(aptr + (kb + 1) * 16 + 4);
      *(float4*)&w_s[nxt][wr][wc4 * 4]     = wv0;
      *(float4*)&w_s[nxt][wr + 8][wc4 * 4] = wv1;
      a_s[nxt][aq + 0][anode] = av0.x; a_s[nxt][aq + 1][anode] = av0.y;
      a_s[nxt][aq + 2][anode] = av0.z; a_s[nxt][aq + 3][anode] = av0.w;
      a_s[nxt][aq + 4][anode] = av1.x; a_s[nxt][aq + 5][anode] = av1.y;
      a_s[nxt][aq + 6][anode] = av1.z; a_s[nxt][aq + 7][anode] = av1.w;
    }
#pragma unroll
    for (int k = 0; k < 16; ++k) {
      float4 w0  = *(const float4*)&w_s[cur][k][tx * 4];
      float4 w1v = *(const float4*)&w_s[cur][k][64 + tx * 4];
      {
        float4 a0 = *(const float4*)&a_s[cur][k][n0];
#pragma unroll
        for (int i = 0; i < 4; ++i) {
          float a = (i == 0) ? a0.x : (i == 1) ? a0.y : (i == 2) ? a0.z : a0.w;
          acc[i][0] = fmaf(a, w0.x,  acc[i][0]);
          acc[i][1] = fmaf(a, w0.y,  acc[i][1]);
          acc[i][2] = fmaf(a, w0.z,  acc[i][2]);
          acc[i][3] = fmaf(a, w0.w,  acc[i][3]);
          acc[i][4] = fmaf(a, w1v.x, acc[i][4]);
          acc[i][5] = fmaf(a, w1v.y, acc[i][5]);
          acc[i][6] = fmaf(a, w1v.z, acc[i][6]);
          acc[i][7] = fmaf(a, w1v.w, acc[i][7]);
        }
      }
      {
        float4 a1 = *(const float4*)&a_s[cur][k][n0 + 4];
#pragma unroll
        for (int i = 0; i < 4; ++i) {
          float a = (i == 0) ? a1.x : (i == 1) ? a1.y : (i == 2) ? a1.z : a1.w;
          acc[4 + i][0] = fmaf(a, w0.x,  acc[4 + i][0]);
          acc[4 + i][1] = fmaf(a, w0.y,  acc[4 + i][1]);
          acc[4 + i][2] = fmaf(a, w0.z,  acc[4 + i][2]);
          acc[4 + i][3] = fmaf(a, w0.w,  acc[4 + i][3]);
          acc[4 + i][4] = fmaf(a, w1v.x, acc[4 + i][4]);
          acc[4 + i][5] = fmaf(a, w1v.y, acc[4 + i][5]);
          acc[4 + i][6] = fmaf(a, w1v.z, acc[4 + i][6]);
          acc[4 + i][7] = fmaf(a, w1v.w, acc[4 + i][7]);
        }
      }
    }
    __syncthreads();
  }

  // + bias: q=0 -> b2[cc*128 + tx*4 + e], q=1 -> +64
  {
    const float* bp = b2 + cc * 128 + tx * 4;
    float4 bq0 = *(const float4*)(bp + 0);
    float4 bq1 = *(const float4*)(bp + 64);
#pragma unroll
    for (int i = 0; i < 8; ++i) {
      acc[i][0] += bq0.x; acc[i][1] += bq0.y; acc[i][2] += bq0.z; acc[i][3] += bq0.w;
      acc[i][4] += bq1.x; acc[i][5] += bq1.y; acc[i][6] += bq1.z; acc[i][7] += bq1.w;
    }
  }

  if (cc < 24) {
    // A/B region: l = q*64+tx*4+e -> i_loc = q*2+(tx>>3), o = (tx&7)*4+e.
    // coef offset = cc*4 + i_loc (A: s1 0..63; B: p 64..95 — contiguous).
    int txh = tx >> 3;
#pragma unroll
    for (int i = 0; i < 8; ++i) {
      const float* cfp = coef_glob + (size_t)(nbase + n0 + i) * 192 + cc * 4 + txh;
      float cf0 = cfp[0];  // q=0 (i_loc = txh)
      float cf1 = cfp[2];  // q=1 (i_loc = 2+txh)
      float* dst = acc_glob + (size_t)(nbase + n0 + i) * ACCW + (tx & 7) * 4;
#pragma unroll
      for (int e = 0; e < 4; ++e) {
        float v = acc[i][e] * cf0 + acc[i][4 + e] * cf1;
        v += __shfl_xor(v, 8);
        if (tx < 8) atomicAdd(&dst[e], v);
      }
    }
  } else if (cc < 32) {
    // C region: i = (cc-24)*8 + q*4 + (tx>>2), o = (tx&3)*4+e; s1 coefs.
    int txq = tx >> 2;
#pragma unroll
    for (int i = 0; i < 8; ++i) {
      const float* cfp = coef_glob + (size_t)(nbase + n0 + i) * 192 + (cc - 24) * 8 + txq;
      float cf0 = cfp[0];  // q=0
      float cf1 = cfp[4];  // q=1
      float* dst = acc_glob + (size_t)(nbase + n0 + i) * ACCW + 32 + (tx & 3) * 4;
#pragma unroll
      for (int e = 0; e < 4; ++e) {
        float v = acc[i][e] * cf0 + acc[i][4 + e] * cf1;
        v += __shfl_xor(v, 4);
        v += __shfl_xor(v, 8);
        if (tx < 4) atomicAdd(&dst[e], v);
      }
    }
  } else {
    // D region: i = (cc-32)*8 + q*4 + (tx>>2), o = (tx&3)*4+e; v1 3-vec coefs.
    int txq = tx >> 2;
#pragma unroll
    for (int i = 0; i < 8; ++i) {
      const float* cfp = coef_glob + (size_t)(nbase + n0 + i) * 192 + 96 +
                         ((cc - 32) * 8 + txq) * 3;
      float* dstb = acc_glob + (size_t)(nbase + n0 + i) * ACCW + 48 + (tx & 3) * 4;
#pragma unroll
      for (int comp = 0; comp < 3; ++comp) {
        float cf0 = cfp[comp];       // q=0
        float cf1 = cfp[12 + comp];  // q=1 (i+4 -> +12 floats)
#pragma unroll
        for (int e = 0; e < 4; ++e) {
          float v = acc[i][e] * cf0 + acc[i][4 + e] * cf1;
          v += __shfl_xor(v, 4);
          v += __shfl_xor(v, 8);
          if (tx < 4) atomicAdd(&dstb[comp * 16 + e], v);
        }
      }
    }
  }
}

// ---------------- combine 96 slots/node -> v_abs[b][80] ----------------
__global__ void k_combine(const int* __restrict__ count, const float* __restrict__ acc_glob,
                          const float* __restrict__ meta_f, const int* __restrict__ meta_b,
                          float* vabs) {
  int g = blockIdx.x * 256 + threadIdx.x;
  int pos = g / ACCW, slot = g - pos * ACCW;
  if (pos >= *count) return;
  const float* acc = acc_glob + (size_t)pos * ACCW;
  float sc = meta_f[pos * 4 + 3] * 0.10206207261596577f;  // gate*env / sqrt(96)
  float* vb = vabs + meta_b[pos] * 80;
  if (slot < 32) {
    atomicAdd(&vb[slot], acc[slot] * sc);
  } else if (slot < 48) {
    int o = slot - 32;
    float q = acc[slot] * sc;
    atomicAdd(&vb[32 + o * 3 + 0], q * meta_f[pos * 4 + 0]);
    atomicAdd(&vb[32 + o * 3 + 1], q * meta_f[pos * 4 + 1]);
    atomicAdd(&vb[32 + o * 3 + 2], q * meta_f[pos * 4 + 2]);
  } else {
    int s2 = slot - 48;          // comp*16 + o
    int comp = s2 >> 4, o = s2 & 15;
    atomicAdd(&vb[32 + o * 3 + comp], acc[slot] * sc);
  }
}

// ---------------- edge-feature scales -> scale_full[512][80] ----------------
__global__ void k_scales(const float* __restrict__ e_feat,
                         const float* __restrict__ we1, const float* __restrict__ be1,
                         const float* __restrict__ we2, const float* __restrict__ be2,
                         float* sfull) {
  int row = blockIdx.x;  // 512
  int t = threadIdx.x;   // 128
  __shared__ float hid[128];
  const float* ef = e_feat + row * 16;
  float s = be1[t];
  for (int k = 0; k < 16; ++k) s = fmaf(ef[k], we1[k * 128 + t], s);
  hid[t] = silu_f(s);
  __syncthreads();
  if (t < 48) {
    float o = be2[t];
    for (int k = 0; k < 128; ++k) o = fmaf(hid[k], we2[k * 48 + t], o);
    if (t < 32) sfull[row * 80 + t] = o;
    else {
      int oo = t - 32;
      sfull[row * 80 + 32 + oo * 3 + 0] = o;
      sfull[row * 80 + 32 + oo * 3 + 1] = o;
      sfull[row * 80 + 32 + oo * 3 + 2] = o;
    }
  }
}

// ---------------- head G1: build inv + (32768x48)@wo1 + silu -> xg ----------------
__global__ __launch_bounds__(256) void k_hg1(const float* __restrict__ vabs,
                                             const float* __restrict__ sfull,
                                             const float* __restrict__ wo1,
                                             const float* __restrict__ bo1,
                                             float* __restrict__ xg) {
  int rbase = blockIdx.x * 64;   // 512 blocks
  int b = rbase >> 9;
  int e0 = rbase & 511;
  int t = threadIdx.x;
  int tx = t & 15, ty = t >> 4;
  int n0 = ty * 4;

  __shared__ float w_s[48 * 128];   // [k][col], 24 KB
  __shared__ float invt[48][64];    // [k][row], 12 KB
  __shared__ float va[80];

  if (t < 80) va[t] = vabs[b * 80 + t];
  {
    const float4* wg = (const float4*)wo1;
    float4* ws4 = (float4*)w_s;
#pragma unroll
    for (int it = 0; it < 6; ++it) ws4[t + it * 256] = wg[t + it * 256];
  }
  __syncthreads();

  for (int idx = t; idx < 48 * 64; idx += 256) {
    int cd = idx >> 6, r = idx & 63;
    const float* sf = sfull + (size_t)(e0 + r) * 80;
    float v;
    if (cd < 32) v = va[cd] * sf[cd];
    else {
      int base = 32 + (cd - 32) * 3;
      float m0 = va[base + 0] * sf[base + 0];
      float m1 = va[base + 1] * sf[base + 1];
      float m2 = va[base + 2] * sf[base + 2];
      v = sqrtf(m0 * m0 + m1 * m1 + m2 * m2 + 1e-12f);
    }
    invt[cd][r] = v;
  }
  __syncthreads();

  float acc[4][8];
#pragma unroll
  for (int i = 0; i < 4; ++i)
#pragma unroll
    for (int j = 0; j < 8; ++j) acc[i][j] = 0.f;

  for (int k = 0; k < 48; ++k) {
    float4 av  = *(const float4*)&invt[k][n0];
    float4 w0  = *(const float4*)&w_s[k * 128 + tx * 4];
    float4 w1v = *(const float4*)&w_s[k * 128 + 64 + tx * 4];
#pragma unroll
    for (int i = 0; i < 4; ++i) {
      float a = (i == 0) ? av.x : (i == 1) ? av.y : (i == 2) ? av.z : av.w;
      acc[i][0] = fmaf(a, w0.x,  acc[i][0]);
      acc[i][1] = fmaf(a, w0.y,  acc[i][1]);
      acc[i][2] = fmaf(a, w0.z,  acc[i][2]);
      acc[i][3] = fmaf(a, w0.w,  acc[i][3]);
      acc[i][4] = fmaf(a, w1v.x, acc[i][4]);
      acc[i][5] = fmaf(a, w1v.y, acc[i][5]);
      acc[i][6] = fmaf(a, w1v.z, acc[i][6]);
      acc[i][7] = fmaf(a, w1v.w, acc[i][7]);
    }
  }

  float4 bq0 = *(const float4*)(bo1 + tx * 4);
  float4 bq1 = *(const float4*)(bo1 + 64 + tx * 4);
#pragma unroll
  for (int i = 0; i < 4; ++i) {
    float* dst = xg + (size_t)(rbase + n0 + i) * 128 + tx * 4;
    *(float4*)dst = make_float4(silu_f(acc[i][0] + bq0.x), silu_f(acc[i][1] + bq0.y),
                                silu_f(acc[i][2] + bq0.z), silu_f(acc[i][3] + bq0.w));
    *(float4*)(dst + 64) = make_float4(silu_f(acc[i][4] + bq1.x), silu_f(acc[i][5] + bq1.y),
                                       silu_f(acc[i][6] + bq1.z), silu_f(acc[i][7] + bq1.w));
  }
}

// ---------------- head G2: (32768x128)@wo2 + silu, IN-PLACE on xg ----------------
__global__ __launch_bounds__(256) void k_hg2(const float* __restrict__ wo2,
                                             const float* __restrict__ bo2,
                                             float* __restrict__ xg) {
  int rbase = blockIdx.x * 64;   // 512 blocks
  int t = threadIdx.x;
  int tx = t & 15, ty = t >> 4;
  int n0 = ty * 4;

  __shared__ float w_s[2][16][128];
  __shared__ float a_s[2][16][64];

  int wr = t >> 5, wc4 = t & 31;
  int anode = t >> 2, aq = t & 3;
  const float* aptr = xg + (size_t)(rbase + anode) * 128 + aq * 4;

  float4 wpre0, wpre1, apre;
  wpre0 = *(const float4*)(wo2 + (size_t)wr * 128 + wc4 * 4);
  wpre1 = *(const float4*)(wo2 + (size_t)(wr + 8) * 128 + wc4 * 4);
  apre  = *(const float4*)aptr;
  *(float4*)&w_s[0][wr][wc4 * 4]     = wpre0;
  *(float4*)&w_s[0][wr + 8][wc4 * 4] = wpre1;
  a_s[0][aq * 4 + 0][anode] = apre.x;
  a_s[0][aq * 4 + 1][anode] = apre.y;
  a_s[0][aq * 4 + 2][anode] = apre.z;
  a_s[0][aq * 4 + 3][anode] = apre.w;
  __syncthreads();

  float acc[4][8];
#pragma unroll
  for (int i = 0; i < 4; ++i)
#pragma unroll
    for (int j = 0; j < 8; ++j) acc[i][j] = 0.f;

  for (int kb = 0; kb < 8; ++kb) {
    int cur = kb & 1;
    if (kb < 7) {
      wpre0 = *(const float4*)(wo2 + (size_t)((kb + 1) * 16 + wr) * 128 + wc4 * 4);
      wpre1 = *(const float4*)(wo2 + (size_t)((kb + 1) * 16 + wr + 8) * 128 + wc4 * 4);
      apre  = *(const float4*)(aptr + (kb + 1) * 16);
    }
#pragma unroll
    for (int k = 0; k < 16; ++k) {
      float4 av  = *(const float4*)&a_s[cur][k][n0];
      float4 w0  = *(const float4*)&w_s[cur][k][tx * 4];
      float4 w1v = *(const float4*)&w_s[cur][k][64 + tx * 4];
#pragma unroll
      for (int i = 0; i < 4; ++i) {
        float a = (i == 0) ? av.x : (i == 1) ? av.y : (i == 2) ? av.z : av.w;
        acc[i][0] = fmaf(a, w0.x,  acc[i][0]);
        acc[i][1] = fmaf(a, w0.y,  acc[i][1]);
        acc[i][2] = fmaf(a, w0.z,  acc[i][2]);
        acc[i][3] = fmaf(a, w0.w,  acc[i][3]);
        acc[i][4] = fmaf(a, w1v.x, acc[i][4]);
        acc[i][5] = fmaf(a, w1v.y, acc[i][5]);
        acc[i][6] = fmaf(a, w1v.z, acc[i][6]);
        acc[i][7] = fmaf(a, w1v.w, acc[i][7]);
      }
    }
    if (kb < 7) {
      int nxt = cur ^ 1;
      *(float4*)&w_s[nxt][wr][wc4 * 4]     = wpre0;
      *(float4*)&w_s[nxt][wr + 8][wc4 * 4] = wpre1;
      a_s[nxt][aq * 4 + 0][anode] = apre.x;
      a_s[nxt][aq * 4 + 1][anode] = apre.y;
      a_s[nxt][aq * 4 + 2][anode] = apre.z;
      a_s[nxt][aq * 4 + 3][anode] = apre.w;
    }
    __syncthreads();
  }

  float4 bq0 = *(const float4*)(bo2 + tx * 4);
  float4 bq1 = *(const float4*)(bo2 + 64 + tx * 4);
#pragma unroll
  for (int i = 0; i < 4; ++i) {
    float* dst = xg + (size_t)(rbase + n0 + i) * 128 + tx * 4;
    *(float4*)dst = make_float4(silu_f(acc[i][0] + bq0.x), silu_f(acc[i][1] + bq0.y),
                                silu_f(acc[i][2] + bq0.z), silu_f(acc[i][3] + bq0.w));
    *(float4*)(dst + 64) = make_float4(silu_f(acc[i][4] + bq1.x), silu_f(acc[i][5] + bq1.y),
                                       silu_f(acc[i][6] + bq1.z), silu_f(acc[i][7] + bq1.w));
  }
}

// ---------------- head G3: (32768x128)@wo3 + bo3 -> out ----------------
__global__ __launch_bounds__(256) void k_hg3(const float* __restrict__ xg,
                                             const float* __restrict__ wo3,
                                             const float* __restrict__ bo3,
                                             float* __restrict__ out) {
  int cc = blockIdx.x;            // 0..1 (col chunk of 128)
  int rbase = blockIdx.y * 64;    // 512
  int t = threadIdx.x;
  int tx = t & 15, ty = t >> 4;
  int n0 = ty * 4;

  __shared__ float w_s[2][16][128];
  __shared__ float a_s[2][16][64];

  const float* wbase = wo3 + cc * 128;
  int wr = t >> 5, wc4 = t & 31;
  int anode = t >> 2, aq = t & 3;
  const float* aptr = xg + (size_t)(rbase + anode) * 128 + aq * 4;

  float4 wpre0, wpre1, apre;
  wpre0 = *(const float4*)(wbase + (size_t)wr * 256 + wc4 * 4);
  wpre1 = *(const float4*)(wbase + (size_t)(wr + 8) * 256 + wc4 * 4);
  apre  = *(const float4*)aptr;
  *(float4*)&w_s[0][wr][wc4 * 4]     = wpre0;
  *(float4*)&w_s[0][wr + 8][wc4 * 4] = wpre1;
  a_s[0][aq * 4 + 0][anode] = apre.x;
  a_s[0][aq * 4 + 1][anode] = apre.y;
  a_s[0][aq * 4 + 2][anode] = apre.z;
  a_s[0][aq * 4 + 3][anode] = apre.w;
  __syncthreads();

  float acc[4][8];
#pragma unroll
  for (int i = 0; i < 4; ++i)
#pragma unroll
    for (int j = 0; j < 8; ++j) acc[i][j] = 0.f;

  for (int kb = 0; kb < 8; ++kb) {
    int cur = kb & 1;
    if (kb < 7) {
      wpre0 = *(const float4*)(wbase + (size_t)((kb + 1) * 16 + wr) * 256 + wc4 * 4);
      wpre1 = *(const float4*)(wbase + (size_t)((kb + 1) * 16 + wr + 8) * 256 + wc4 * 4);
      apre  = *(const float4*)(aptr + (kb + 1) * 16);
    }
#pragma unroll
    for (int k = 0; k < 16; ++k) {
      float4 av  = *(const float4*)&a_s[cur][k][n0];
      float4 w0  = *(const float4*)&w_s[cur][k][tx * 4];
      float4 w1v = *(const float4*)&w_s[cur][k][64 + tx * 4];
#pragma unroll
      for (int i = 0; i < 4; ++i) {
        float a = (i == 0) ? av.x : (i == 1) ? av.y : (i == 2) ? av.z : av.w;
        acc[i][0] = fmaf(a, w0.x,  acc[i][0]);
        acc[i][1] = fmaf(a, w0.y,  acc[i][1]);
        acc[i][2] = fmaf(a, w0.z,  acc[i][2]);
        acc[i][3] = fmaf(a, w0.w,  acc[i][3]);
        acc[i][4] = fmaf(a, w1v.x, acc[i][4]);
        acc[i][5] = fmaf(a, w1v.y, acc[i][5]);
        acc[i][6] = fmaf(a, w1v.z, acc[i][6]);
        acc[i][7] = fmaf(a, w1v.w, acc[i][7]);
      }
    }
    if (kb < 7) {
      int nxt = cur ^ 1;
      *(float4*)&w_s[nxt][wr][wc4 * 4]     = wpre0;
      *(float4*)&w_s[nxt][wr + 8][wc4 * 4] = wpre1;
      a_s[nxt][aq * 4 + 0][anode] = apre.x;
      a_s[nxt][aq * 4 + 1][anode] = apre.y;
      a_s[nxt][aq * 4 + 2][anode] = apre.z;
      a_s[nxt][aq * 4 + 3][anode] = apre.w;
    }
    __syncthreads();
  }

  const float* bp = bo3 + cc * 128 + tx * 4;
  float4 bq0 = *(const float4*)(bp + 0);
  float4 bq1 = *(const float4*)(bp + 64);
#pragma unroll
  for (int i = 0; i < 4; ++i) {
    float* dst = out + (size_t)(rbase + n0 + i) * 256 + cc * 128 + tx * 4;
    *(float4*)dst = make_float4(acc[i][0] + bq0.x, acc[i][1] + bq0.y,
                                acc[i][2] + bq0.z, acc[i][3] + bq0.w);
    *(float4*)(dst + 64) = make_float4(acc[i][4] + bq1.x, acc[i][5] + bq1.y,
                                       acc[i][6] + bq1.z, acc[i][7] + bq1.w);
  }
}

extern "C" void kernel_launch(void* const* d_in, const int* in_sizes, int n_in,
                              void* d_out, int out_size, void* d_ws, size_t ws_size,
                              hipStream_t stream) {
  const float* h        = (const float*)d_in[0];
  const float* h_full   = (const float*)d_in[1];
  const int*   z        = (const int*)d_in[2];
  const float* e_feat   = (const float*)d_in[4];
  const int*   abs_idx  = (const int*)d_in[5];
  const int*   att_dst  = (const int*)d_in[6];
  const float* att_dist = (const float*)d_in[7];
  const float* att_vec  = (const float*)d_in[8];
  const float* w_zemb   = (const float*)d_in[9];
  const float* w1_rad   = (const float*)d_in[10];
  const float* b1_rad   = (const float*)d_in[11];
  const float* w2_rad   = (const float*)d_in[12];
  const float* b2_rad   = (const float*)d_in[13];
  const float* wg1      = (const float*)d_in[14];
  const float* bg1      = (const float*)d_in[15];
  const float* wg2      = (const float*)d_in[16];
  const float* bg2      = (const float*)d_in[17];
  const float* we1      = (const float*)d_in[18];
  const float* be1      = (const float*)d_in[19];
  const float* we2      = (const float*)d_in[20];
  const float* be2      = (const float*)d_in[21];
  const float* wo1      = (const float*)d_in[22];
  const float* bo1      = (const float*)d_in[23];
  const float* wo2      = (const float*)d_in[24];
  const float* bo2      = (const float*)d_in[25];
  const float* wo3      = (const float*)d_in[26];
  const float* bo3      = (const float*)d_in[27];
  float* out = (float*)d_out;

  // workspace layout (~17.2 MB): persistent small buffers first, then a
  // region where phase-1 (a/coef/acc, 6.8 MB) and phase-2 (xg, 16.8 MB) alias.
  float* meta_f  = (float*)d_ws;                 // MAXACT*4
  float* vabs    = meta_f + MAXACT * 4;          // 64*80
  float* sfull   = vabs + NB * OD_;              // 512*80
  float* habs_g  = sfull + NE_ * OD_;            // 64*128
  int* widx   = (int*)(habs_g + NB * 128);       // 8192
  int* active = widx + FLAT;                     // 4096
  int* meta_b = active + MAXACT;                 // 4096
  int* count  = meta_b + MAXACT;                 // 1 (+pad to 16B)
  float* big  = (float*)(count + 15);            // aligned big region
  float* a_glob    = big;                        // MAXACT*128   (phase 1)
  float* coef_glob = a_glob + MAXACT * 128;      // MAXACT*192   (phase 1)
  float* acc_glob  = coef_glob + MAXACT * 192;   // MAXACT*96    (phase 1)
  float* xg        = big;                        // 32768*128    (phase 2, aliases phase 1)

  k_init<<<1536, 256, 0, stream>>>(acc_glob, vabs, widx, count);
  k_scatter<<<16, 256, 0, stream>>>(att_dst, widx);
  k_build<<<32, 256, 0, stream>>>(widx, active, count);
  k_gabs<<<NB, 128, 0, stream>>>(abs_idx, h, wg1, habs_g);
  k_node<<<MAXACT, 128, 0, stream>>>(count, active, widx, att_dist, att_vec, z, w_zemb,
                                     abs_idx, w1_rad, b1_rad, h, habs_g, wg1, bg1, wg2, bg2,
                                     h_full, a_glob, coef_glob, meta_f, meta_b);
  k_rgemm<<<dim3(36, 32), 256, 0, stream>>>(count, a_glob, coef_glob, w2_rad, b2_rad,
                                            acc_glob);
  k_combine<<<1536, 256, 0, stream>>>(count, acc_glob, meta_f, meta_b, vabs);
  k_scales<<<512, 128, 0, stream>>>(e_feat, we1, be1, we2, be2, sfull);
  k_hg1<<<512, 256, 0, stream>>>(vabs, sfull, wo1, bo1, xg);
  k_hg2<<<512, 256, 0, stream>>>(wo2, bo2, xg);
  k_hg3<<<dim3(2, 512), 256, 0, stream>>>(xg, wo3, bo3, out);
}